// Round 8
// baseline (457.183 us; speedup 1.0000x reference)
//
#include <hip/hip_runtime.h>
#include <stdint.h>

#define HW 16384
#define CDIM 768
#define EPSF 1e-8f

typedef float f32x4  __attribute__((ext_vector_type(4)));
typedef float f32x16 __attribute__((ext_vector_type(16)));
typedef int   i32x8  __attribute__((ext_vector_type(8)));
typedef uint32_t u32x4 __attribute__((ext_vector_type(4)));

__device__ inline void async16(const void* g, void* l) {
    __builtin_amdgcn_global_load_lds(
        (const __attribute__((address_space(1))) uint32_t*)g,
        (__attribute__((address_space(3))) uint32_t*)l, 16, 0, 0);
}

__device__ inline uint32_t pk4_fp8(float v0, float v1, float v2, float v3) {
    uint32_t r = __builtin_amdgcn_cvt_pk_fp8_f32(v0, v1, 0, false);
    r = __builtin_amdgcn_cvt_pk_fp8_f32(v2, v3, r, true);
    return r;   // bytes [v0,v1,v2,v3] little-endian
}

// ---- Kernel 1: fused transpose [C][HW] fp32 -> [HW][C] fp8 + column sum-sq ----
__global__ void __launch_bounds__(256)
transpose_fp8_norm(const float* __restrict__ a, const float* __restrict__ b,
                   uint8_t* __restrict__ at8, uint8_t* __restrict__ bn8,
                   float* __restrict__ sumsq_a, float* __restrict__ sumsq_b) {
    const int z = blockIdx.z;
    const float* src = z ? b : a;
    uint8_t* dst = z ? bn8 : at8;
    float* sums = z ? sumsq_b : sumsq_a;
    const float mult = z ? 8.0f : 16.0f;

    __shared__ float tile[64][65];   // [channel][spatial], +1 pad
    const int s0 = blockIdx.x * 64, c0 = blockIdx.y * 64;

    const int lane16 = threadIdx.x & 15, crow = threadIdx.x >> 4;
#pragma unroll
    for (int p = 0; p < 4; ++p) {
        int cl = p * 16 + crow;
        f32x4 v = *(const f32x4*)&src[(size_t)(c0 + cl) * HW + s0 + lane16 * 4];
        tile[cl][lane16 * 4 + 0] = v[0];
        tile[cl][lane16 * 4 + 1] = v[1];
        tile[cl][lane16 * 4 + 2] = v[2];
        tile[cl][lane16 * 4 + 3] = v[3];
    }
    __syncthreads();

    const int tx = threadIdx.x & 63, ty = threadIdx.x >> 6;
    const int chgrp = tx & 15, rowsub = tx >> 4;
    uint32_t* dst32 = (uint32_t*)dst;
#pragma unroll
    for (int p = 0; p < 4; ++p) {
        int sl = p * 16 + ty * 4 + rowsub;
        float v0 = tile[chgrp * 4 + 0][sl];
        float v1 = tile[chgrp * 4 + 1][sl];
        float v2 = tile[chgrp * 4 + 2][sl];
        float v3 = tile[chgrp * 4 + 3][sl];
        float part = v0 * v0 + v1 * v1 + v2 * v2 + v3 * v3;  // raw sum-sq
        dst32[(size_t)(s0 + sl) * (CDIM / 4) + (c0 >> 2) + chgrp] =
            pk4_fp8(v0 * mult, v1 * mult, v2 * mult, v3 * mult);
#pragma unroll
        for (int m = 1; m < 16; m <<= 1) part += __shfl_xor(part, m, 64);
        if (chgrp == 0) atomicAdd(&sums[s0 + sl], part);
    }
}

// ---- Kernel 1b: precompute inverse denominators for b (after atomics) ----
__global__ void prep_invd(const float* __restrict__ sumsq_b,
                          float* __restrict__ invdb) {
    int j = blockIdx.x * 256 + threadIdx.x;
    invdb[j] = 1.0f / (sqrtf(sumsq_b[j] + EPSF) + EPSF);
}

// ---- Kernel 2: MX-scaled fp8 GEMM + normalize + argmax epilogue ----
// Round 16: combine the two proven halves that were never tested together:
//  - r7 GEOMETRY: 128i x 256j block, 8 waves (2i x 4j), 64x64 wave tile,
//    64 VGPR + 64 AGPR/wave -> 43% occupancy (2 blocks/CU by LDS).
//  - r6 SCHEDULE: rolled 3-buffer counted-vmcnt pipeline. r7's budget:
//    LDS pipe ~165us/CU busy vs 291us measured = 57% efficiency; the
//    per-K-step WAITN(0)+barrier (1 compute phase of cover) exposes
//    latency. Counted WAITN(3): at the wait, tiles t+1,t+2 in flight
//    (6 issues/wave); drain to 3 = tile t+1 landed, tile t+2's loads
//    CROSS the barrier -> every tile gets 2 compute phases + a barrier
//    of cover. r6 proved this schedule correct (WAR: buf staged at iter
//    t was computed at iter t-1; reads consumed by MFMA lgkm deps before
//    that barrier) and spill-free when ROLLED (runtime buffer scalars,
//    unroll 1 -- the r5 spill came from 6x macro expansion only).
// LDS 3 x 24KB = 72KB -> 2 blocks/CU (144KB). WRITE_SIZE is the spill
// sentinel: must stay 33MB.
// Same 64B-row swizzle involution (write chunk (lane&3)^((lane>>3)&3),
// read key ^((l31>>1)&3)); swapped operands -> lane-local argmax.
// C/D 32x32: col=lane&31, row=(reg&3)+8*(reg>>2)+4*(lane>>5).
__global__ void
gemm_argmax(const uint8_t* __restrict__ at8, const uint8_t* __restrict__ bn8,
            const float* __restrict__ invdb,
            unsigned long long* __restrict__ best) {
    __shared__ uint8_t Al[3 * 8192];    // [buf][128 rows][64 B]
    __shared__ uint8_t Bl[3 * 16384];   // [buf][256 rows][64 B]

    const int g = blockIdx.x;          // 0..8191
    const int xcd    = g & 7;
    const int s      = g >> 3;         // 0..1023
    const int super  = s >> 5;         // 0..31 = si(2b) x sj(3b)
    const int within = s & 31;         // 32 blocks / supertile (4i x 8j)
    const int si = super >> 3;         // 0..3
    const int sj = super & 7;          // 0..7
    const int it = xcd * 16 + si * 4 + (within & 3);   // 0..127
    const int jt = sj * 8 + (within >> 2);             // 0..63

    const int i0 = it * 128, j0 = jt * 256;
    const int tid = threadIdx.x;       // 512 threads = 8 waves
    const int lane = tid & 63, w = tid >> 6;
    const int wi = w & 1, wj = w >> 1;   // wave grid 2i x 4j
    const int l31 = lane & 31, hi = lane >> 5;

    f32x16 acc[2][2] = {};   // [nj][mi]: rows j (regs), cols i (lanes)

    // staging (per 1KB issue: 16 rows x 64B): lane l -> row (l>>2),
    // global chunk (l&3)^((l>>3)&3) [== (row>>1)&3], LDS linear.
    // wave w: A rows [w*16, w*16+16) (1 issue), B rows [w*32, w*32+32)
    // (2 issues) -> 3 async16/wave/tile.
    const int srow = lane >> 2;
    const int schunk = ((lane & 3) ^ ((lane >> 3) & 3)) * 16;
    const uint8_t* gAs = at8 + (size_t)(i0 + w * 16 + srow) * CDIM + schunk;
    const uint8_t* gBs = bn8 + (size_t)(j0 + w * 32 + srow) * CDIM + schunk;
    uint8_t* lA = Al + w * 1024;
    uint8_t* lB = Bl + w * 2048;

    // fragment reads: A row = wi*64 + mi*32 + l31; B row = wj*64 + nj*32 + l31
    // lane K-bytes hi*32.. -> logical chunks hi*2, hi*2+1; phys = ^((row>>1)&3)
    const int rA0 = (wi * 64 + l31) * 64;
    const int rB0 = (wj * 64 + l31) * 64;
    const int c0 = ((hi * 2) ^ ((l31 >> 1) & 3)) * 16;   // pair at c0^16

#define STAGE(boA, boB)                                        \
    do {                                                       \
        async16(gAs,             lA + (boA));                  \
        async16(gBs,             lB + (boB));                  \
        async16(gBs + 16 * CDIM, lB + (boB) + 1024);           \
        gAs += 64; gBs += 64;                                  \
    } while (0)

#define COMPUTE(boA, boB)                                                    \
    do {                                                                     \
        i32x8 af0, af1, bg;                                                  \
        *(u32x4*)&af0       = *(const u32x4*)&Al[(boA) + rA0 + c0];          \
        *((u32x4*)&af0 + 1) = *(const u32x4*)&Al[(boA) + rA0 + (c0 ^ 16)];   \
        *(u32x4*)&af1       = *(const u32x4*)&Al[(boA) + rA0 + 2048 + c0];   \
        *((u32x4*)&af1 + 1) = *(const u32x4*)&Al[(boA) + rA0 + 2048 + (c0 ^ 16)]; \
        *(u32x4*)&bg        = *(const u32x4*)&Bl[(boB) + rB0 + c0];          \
        *((u32x4*)&bg + 1)  = *(const u32x4*)&Bl[(boB) + rB0 + (c0 ^ 16)];   \
        __builtin_amdgcn_s_setprio(1);                                       \
        acc[0][0] = __builtin_amdgcn_mfma_scale_f32_32x32x64_f8f6f4(         \
            bg, af0, acc[0][0], 0, 0, 0, 0x7F7F7F7F, 0, 0x7F7F7F7F);         \
        acc[0][1] = __builtin_amdgcn_mfma_scale_f32_32x32x64_f8f6f4(         \
            bg, af1, acc[0][1], 0, 0, 0, 0x7F7F7F7F, 0, 0x7F7F7F7F);         \
        __builtin_amdgcn_s_setprio(0);                                       \
        *(u32x4*)&bg        = *(const u32x4*)&Bl[(boB) + rB0 + 2048 + c0];   \
        *((u32x4*)&bg + 1)  = *(const u32x4*)&Bl[(boB) + rB0 + 2048 + (c0 ^ 16)]; \
        __builtin_amdgcn_s_setprio(1);                                       \
        acc[1][0] = __builtin_amdgcn_mfma_scale_f32_32x32x64_f8f6f4(         \
            bg, af0, acc[1][0], 0, 0, 0, 0x7F7F7F7F, 0, 0x7F7F7F7F);         \
        acc[1][1] = __builtin_amdgcn_mfma_scale_f32_32x32x64_f8f6f4(         \
            bg, af1, acc[1][1], 0, 0, 0, 0x7F7F7F7F, 0, 0x7F7F7F7F);         \
        __builtin_amdgcn_s_setprio(0);                                       \
    } while (0)

#define WAITN(n) asm volatile("s_waitcnt vmcnt(" #n ")" ::: "memory")

    // prologue: stage tiles 0 (buf0) and 1 (buf1); wait tile 0 only.
    STAGE(0, 0);
    STAGE(8192, 16384);
    WAITN(3);                              // tile 0 landed, tile 1 in flight
    __builtin_amdgcn_s_barrier();

    // rolled steady state: iter t stages tile t+2 (buf bs), computes
    // tile t (buf bc). At WAITN(3): 6 issues in flight (t+1, t+2);
    // drain tile t+1 only -- tile t+2's loads cross the barrier.
    int bc = 0, bs = 2;
#pragma unroll 1
    for (int t = 0; t < 10; ++t) {
        STAGE(bs * 8192, bs * 16384);
        COMPUTE(bc * 8192, bc * 16384);
        WAITN(3);                          // tile t+1 landed (t+2 in flight)
        __builtin_amdgcn_s_barrier();
        bc = (bc == 2) ? 0 : bc + 1;
        bs = (bs == 2) ? 0 : bs + 1;
    }
    COMPUTE(1 * 8192, 1 * 16384);          // tile 10 (buf 1)
    WAITN(0);                              // tile 11 landed
    __builtin_amdgcn_s_barrier();
    COMPUTE(2 * 8192, 2 * 16384);          // tile 11 (buf 2)

#undef STAGE
#undef COMPUTE
#undef WAITN

    // epilogue: normalize by per-j inv-denom (precomputed, reg-indexed),
    // lane-local argmax over 32 j's per mi, one hi-exchange + atomicMax.
    float bv[2] = {-1e30f, -1e30f};
    int   bj[2] = {0, 0};
#pragma unroll
    for (int nj = 0; nj < 2; ++nj) {
        const int jb = j0 + wj * 64 + nj * 32 + 4 * hi;
        f32x4 iv[4];
#pragma unroll
        for (int q = 0; q < 4; ++q)
            iv[q] = *(const f32x4*)&invdb[jb + 8 * q];
#pragma unroll
        for (int mi = 0; mi < 2; ++mi) {
#pragma unroll
            for (int r = 0; r < 16; ++r) {
                int j = jb + (r & 3) + 8 * (r >> 2);
                float v = acc[nj][mi][r] * iv[r >> 2][r & 3];
                if (v > bv[mi] || (v == bv[mi] && j < bj[mi])) {
                    bv[mi] = v; bj[mi] = j;
                }
            }
        }
    }
#pragma unroll
    for (int mi = 0; mi < 2; ++mi) {
        float ov = __shfl_xor(bv[mi], 32, 64);
        int   oj = __shfl_xor(bj[mi], 32, 64);
        if (ov > bv[mi] || (ov == bv[mi] && oj < bj[mi])) {
            bv[mi] = ov; bj[mi] = oj;
        }
        if (hi == 0) {
            int gi = i0 + wi * 64 + mi * 32 + l31;
            uint32_t u = __float_as_uint(bv[mi]);
            u = (u & 0x80000000u) ? ~u : (u | 0x80000000u);  // orderable f32
            unsigned long long packed =
                ((unsigned long long)u << 32) | (uint32_t)(~(uint32_t)bj[mi]);
            atomicMax(&best[gi], packed);  // ties -> larger ~j -> smaller j
        }
    }
}

// ---- Kernel 3: final loss from stored argmax dot (no gather) ----
// stored v = 128 * dot(a_i, b_j) / denom_b[j]  (fp8 dot, fp32 denom)
__global__ void loss_reduce(const unsigned long long* __restrict__ best,
                            const float* __restrict__ sumsq_a,
                            const float* __restrict__ sumsq_b,
                            float* __restrict__ out) {
    int i = blockIdx.x * 256 + threadIdx.x;
    unsigned long long pk = best[i];
    uint32_t x = (uint32_t)(pk >> 32);
    float v = (x & 0x80000000u) ? __uint_as_float(x & 0x7fffffffu)
                                : __uint_as_float(~x);
    int j = (int)(~(uint32_t)pk);
    float sb = sumsq_b[j];
    float denb = sqrtf(sb + EPSF) + EPSF;
    float dot = v * denb * (1.0f / 128.0f);
    float cs = dot / ((sqrtf(sumsq_a[i]) + EPSF) * (sqrtf(sb) + EPSF));
    float term = 1.0f - cs;
#pragma unroll
    for (int m = 32; m; m >>= 1) term += __shfl_down(term, m, 64);
    __shared__ float red[4];
    int wv = threadIdx.x >> 6, lane = threadIdx.x & 63;
    if (lane == 0) red[wv] = term;
    __syncthreads();
    if (threadIdx.x == 0) {
        float ssum = (red[0] + red[1] + red[2] + red[3]) * (1.0f / HW);
        atomicAdd(out, ssum);
    }
}

extern "C" void kernel_launch(void* const* d_in, const int* in_sizes, int n_in,
                              void* d_out, int out_size, void* d_ws, size_t ws_size,
                              hipStream_t stream) {
    const float* a = (const float*)d_in[0];
    const float* b = (const float*)d_in[1];
    char* ws = (char*)d_ws;

    const size_t T_BYTES = (size_t)HW * CDIM;   // 12.58 MB per fp8 matrix
    uint8_t* at8 = (uint8_t*)ws;
    uint8_t* bn8 = (uint8_t*)(ws + T_BYTES);
    float* sumsq_a = (float*)(ws + 2 * T_BYTES);
    float* sumsq_b = (float*)(ws + 2 * T_BYTES + HW * sizeof(float));
    unsigned long long* best =
        (unsigned long long*)(ws + 2 * T_BYTES + 2 * HW * sizeof(float));
    float* invdb = (float*)(ws + 2 * T_BYTES + 2 * HW * sizeof(float)
                            + HW * sizeof(unsigned long long));

    // zero sumsq_a + sumsq_b + best in one contiguous memset
    hipMemsetAsync(sumsq_a, 0, 2 * HW * sizeof(float) + HW * sizeof(unsigned long long),
                   stream);
    hipMemsetAsync(d_out, 0, out_size * sizeof(float), stream);

    dim3 tg(HW / 64, CDIM / 64, 2);
    transpose_fp8_norm<<<tg, 256, 0, stream>>>(a, b, at8, bn8, sumsq_a, sumsq_b);
    prep_invd<<<HW / 256, 256, 0, stream>>>(sumsq_b, invdb);
    gemm_argmax<<<(HW / 128) * (HW / 256), 512, 0, stream>>>(at8, bn8, invdb, best);
    loss_reduce<<<HW / 256, 256, 0, stream>>>(best, sumsq_a, sumsq_b, (float*)d_out);
}

// Round 9
// 381.952 us; speedup vs baseline: 1.1970x; 1.1970x over previous
//
#include <hip/hip_runtime.h>
#include <stdint.h>

#define HW 16384
#define CDIM 768
#define EPSF 1e-8f

typedef float f32x4  __attribute__((ext_vector_type(4)));
typedef float f32x16 __attribute__((ext_vector_type(16)));
typedef int   i32x8  __attribute__((ext_vector_type(8)));
typedef uint32_t u32x4 __attribute__((ext_vector_type(4)));

__device__ inline void async16(const void* g, void* l) {
    __builtin_amdgcn_global_load_lds(
        (const __attribute__((address_space(1))) uint32_t*)g,
        (__attribute__((address_space(3))) uint32_t*)l, 16, 0, 0);
}

__device__ inline uint32_t pk4_fp8(float v0, float v1, float v2, float v3) {
    uint32_t r = __builtin_amdgcn_cvt_pk_fp8_f32(v0, v1, 0, false);
    r = __builtin_amdgcn_cvt_pk_fp8_f32(v2, v3, r, true);
    return r;   // bytes [v0,v1,v2,v3] little-endian
}

// ---- Kernel 1: fused transpose [C][HW] fp32 -> [HW][C] fp8 + column sum-sq ----
// Round 17 restructure: one block owns a 64-spatial strip and LOOPS over
// all 12 channel-blocks (was: one block per (s,c) pair + global atomics).
// Sum-sq accumulates in registers across the c-loop -> plain store (no
// atomics -- was 393k -- and no sumsq memset needed). z=1 blocks emit
// invdb directly (prep_invd kernel deleted; one launch fewer).
// z=0: a (scale x16), z=1: b (scale x8, RAW; normalization in epilogue).
__global__ void __launch_bounds__(256)
transpose_fp8_norm(const float* __restrict__ a, const float* __restrict__ b,
                   uint8_t* __restrict__ at8, uint8_t* __restrict__ bn8,
                   float* __restrict__ sumsq_a, float* __restrict__ sumsq_b,
                   float* __restrict__ invdb) {
    const int z = blockIdx.z;
    const float* src = z ? b : a;
    uint8_t* dst = z ? bn8 : at8;
    float* sums = z ? sumsq_b : sumsq_a;
    const float mult = z ? 8.0f : 16.0f;

    __shared__ float tile[64][65];   // [channel][spatial], +1 pad
    const int s0 = blockIdx.x * 64;
    const int tx = threadIdx.x & 63, ty = threadIdx.x >> 6;
    const int chgrp = tx & 15, rowsub = tx >> 4;
    uint32_t* dst32 = (uint32_t*)dst;

    float ss[4] = {0.0f, 0.0f, 0.0f, 0.0f};   // per-p sum-sq accumulators

#pragma unroll 1
    for (int cb = 0; cb < 12; ++cb) {
        const int c0 = cb * 64;
#pragma unroll
        for (int p = 0; p < 16; ++p) {
            int cl = p * 4 + ty;
            tile[cl][tx] = src[(size_t)(c0 + cl) * HW + s0 + tx];
        }
        __syncthreads();
#pragma unroll
        for (int p = 0; p < 4; ++p) {
            int sl = p * 16 + ty * 4 + rowsub;
            float v0 = tile[chgrp * 4 + 0][sl];
            float v1 = tile[chgrp * 4 + 1][sl];
            float v2 = tile[chgrp * 4 + 2][sl];
            float v3 = tile[chgrp * 4 + 3][sl];
            float part = v0 * v0 + v1 * v1 + v2 * v2 + v3 * v3;  // raw sum-sq
            dst32[(size_t)(s0 + sl) * (CDIM / 4) + (c0 >> 2) + chgrp] =
                pk4_fp8(v0 * mult, v1 * mult, v2 * mult, v3 * mult);
#pragma unroll
            for (int m = 1; m < 16; m <<= 1) part += __shfl_xor(part, m, 64);
            ss[p] += part;   // butterfly leaves total in all 16 lanes
        }
        __syncthreads();     // tile reuse fence for next cb
    }

#pragma unroll
    for (int p = 0; p < 4; ++p) {
        int sl = p * 16 + ty * 4 + rowsub;
        if (chgrp == 0) {
            float t = ss[p];
            sums[s0 + sl] = t;                                   // plain store
            if (z) invdb[s0 + sl] = 1.0f / (sqrtf(t + EPSF) + EPSF);
        }
    }
}

// ---- Kernel 2: MX-scaled fp8 GEMM + normalize + argmax epilogue ----
// Round 17: RESTORED round-3 kernel verbatim -- the session's best GEMM
// (280us). Nine configs establish: drain-per-tile + ~44% occupancy =
// 280-291us; counted-vmcnt-across-barrier is 0-for-3 (r5/r8 spill-like
// HBM blowups, r6 slower at equal occupancy) -- technique struck.
// Geometry: 128x128 block, 4 waves, 64x64 wave tile, 64 VGPR + 64 AGPR
// -> 4 waves/SIMD. BK=64 double-buffer: STAGE(t+1) issued before
// COMPUTE(t), drain vmcnt(0) AFTER compute + raw s_barrier.
// Swizzle involution (64B rows): write chunk (lane&3)^((lane>>3)&3),
// read key ^((l31>>1)&3). Swapped operands -> lane-local argmax.
// C/D 32x32: col=lane&31, row=(reg&3)+8*(reg>>2)+4*(lane>>5).
__global__ void
gemm_argmax(const uint8_t* __restrict__ at8, const uint8_t* __restrict__ bn8,
            const float* __restrict__ invdb,
            unsigned long long* __restrict__ best) {
    __shared__ uint8_t Al[2 * 8192];   // [buf][128 rows][64 B]
    __shared__ uint8_t Bl[2 * 8192];

    const int g = blockIdx.x;          // 0..16383
    const int xcd    = g & 7;
    const int s      = g >> 3;
    const int super  = s >> 5;         // 32 blocks / supertile
    const int within = s & 31;
    const int si = super >> 4;         // 4 i-tiles per supertile row
    const int sj = super & 15;         // 8 j-tiles per supertile col
    const int it = xcd * 16 + si * 4 + (within & 3);
    const int jt = sj * 8 + (within >> 2);

    const int i0 = it * 128, j0 = jt * 128;
    const int tid = threadIdx.x;
    const int lane = tid & 63, w = tid >> 6;
    const int wi = w & 1, wj = w >> 1;
    const int l31 = lane & 31, hi = lane >> 5;

    f32x16 acc[2][2] = {};   // [nj][mi]: rows j (regs), cols i (lanes)

    const int srow = lane >> 2;
    const int schunk = ((lane & 3) ^ ((lane >> 3) & 3)) * 16;
    const uint8_t* gA = at8 + (size_t)(i0 + w * 32 + srow) * CDIM + schunk;
    const uint8_t* gB = bn8 + (size_t)(j0 + w * 32 + srow) * CDIM + schunk;
    uint8_t* lA = Al + w * 2048;       // this wave's 32 rows
    uint8_t* lB = Bl + w * 2048;

    const int rA0 = (wi * 64 + l31) * 64;
    const int rB0 = (wj * 64 + l31) * 64;
    const int c0 = ((hi * 2) ^ ((l31 >> 1) & 3)) * 16;   // second b128 at ^16

#define STAGE(bo, kk)                                         \
    do {                                                      \
        async16(gA + (kk),             lA + (bo));            \
        async16(gA + (kk) + 16 * CDIM, lA + (bo) + 1024);     \
        async16(gB + (kk),             lB + (bo));            \
        async16(gB + (kk) + 16 * CDIM, lB + (bo) + 1024);     \
    } while (0)

#define COMPUTE(bo)                                                          \
    do {                                                                     \
        i32x8 af0, af1, bg;                                                  \
        *(u32x4*)&af0       = *(const u32x4*)&Al[(bo) + rA0 + c0];           \
        *((u32x4*)&af0 + 1) = *(const u32x4*)&Al[(bo) + rA0 + (c0 ^ 16)];    \
        *(u32x4*)&af1       = *(const u32x4*)&Al[(bo) + rA0 + 2048 + c0];    \
        *((u32x4*)&af1 + 1) = *(const u32x4*)&Al[(bo) + rA0 + 2048 + (c0 ^ 16)]; \
        *(u32x4*)&bg        = *(const u32x4*)&Bl[(bo) + rB0 + c0];           \
        *((u32x4*)&bg + 1)  = *(const u32x4*)&Bl[(bo) + rB0 + (c0 ^ 16)];    \
        acc[0][0] = __builtin_amdgcn_mfma_scale_f32_32x32x64_f8f6f4(         \
            bg, af0, acc[0][0], 0, 0, 0, 0x7F7F7F7F, 0, 0x7F7F7F7F);         \
        acc[0][1] = __builtin_amdgcn_mfma_scale_f32_32x32x64_f8f6f4(         \
            bg, af1, acc[0][1], 0, 0, 0, 0x7F7F7F7F, 0, 0x7F7F7F7F);         \
        *(u32x4*)&bg        = *(const u32x4*)&Bl[(bo) + rB0 + 2048 + c0];    \
        *((u32x4*)&bg + 1)  = *(const u32x4*)&Bl[(bo) + rB0 + 2048 + (c0 ^ 16)]; \
        acc[1][0] = __builtin_amdgcn_mfma_scale_f32_32x32x64_f8f6f4(         \
            bg, af0, acc[1][0], 0, 0, 0, 0x7F7F7F7F, 0, 0x7F7F7F7F);         \
        acc[1][1] = __builtin_amdgcn_mfma_scale_f32_32x32x64_f8f6f4(         \
            bg, af1, acc[1][1], 0, 0, 0, 0x7F7F7F7F, 0, 0x7F7F7F7F);         \
    } while (0)

    // prologue: stage tile 0, drain, barrier
    STAGE(0, 0);
    asm volatile("s_waitcnt vmcnt(0)" ::: "memory");
    __builtin_amdgcn_s_barrier();

#pragma unroll 1
    for (int t = 0; t < 11; ++t) {
        const int bo = (t & 1) * 8192;
        STAGE(bo ^ 8192, (t + 1) * 64);   // issue next tile (latency hides
        COMPUTE(bo);                      //   under this compute phase)
        asm volatile("s_waitcnt vmcnt(0)" ::: "memory");  // next tile landed
        __builtin_amdgcn_s_barrier();
    }
    COMPUTE(8192);                        // t=11, no further staging

#undef STAGE
#undef COMPUTE

    // epilogue: normalize by per-j inv-denom (precomputed, reg-indexed),
    // lane-local argmax over the 32 j's, one hi-exchange + atomicMax.
    float bv[2] = {-1e30f, -1e30f};
    int   bj[2] = {0, 0};
#pragma unroll
    for (int nj = 0; nj < 2; ++nj) {
        const int jb = j0 + wj * 64 + nj * 32 + 4 * hi;
        f32x4 iv[4];
#pragma unroll
        for (int q = 0; q < 4; ++q)
            iv[q] = *(const f32x4*)&invdb[jb + 8 * q];
#pragma unroll
        for (int mi = 0; mi < 2; ++mi) {
#pragma unroll
            for (int r = 0; r < 16; ++r) {
                int j = jb + (r & 3) + 8 * (r >> 2);
                float v = acc[nj][mi][r] * iv[r >> 2][r & 3];
                if (v > bv[mi] || (v == bv[mi] && j < bj[mi])) {
                    bv[mi] = v; bj[mi] = j;
                }
            }
        }
    }
#pragma unroll
    for (int mi = 0; mi < 2; ++mi) {
        float ov = __shfl_xor(bv[mi], 32, 64);
        int   oj = __shfl_xor(bj[mi], 32, 64);
        if (ov > bv[mi] || (ov == bv[mi] && oj < bj[mi])) {
            bv[mi] = ov; bj[mi] = oj;
        }
        if (hi == 0) {
            int gi = i0 + wi * 64 + mi * 32 + l31;
            uint32_t u = __float_as_uint(bv[mi]);
            u = (u & 0x80000000u) ? ~u : (u | 0x80000000u);  // orderable f32
            unsigned long long packed =
                ((unsigned long long)u << 32) | (uint32_t)(~(uint32_t)bj[mi]);
            atomicMax(&best[gi], packed);  // ties -> larger ~j -> smaller j
        }
    }
}

// ---- Kernel 3: final loss from stored argmax dot (no gather) ----
// stored v = 128 * dot(a_i, b_j) / denom_b[j]  (fp8 dot, fp32 denom)
__global__ void loss_reduce(const unsigned long long* __restrict__ best,
                            const float* __restrict__ sumsq_a,
                            const float* __restrict__ sumsq_b,
                            float* __restrict__ out) {
    int i = blockIdx.x * 256 + threadIdx.x;
    unsigned long long pk = best[i];
    uint32_t x = (uint32_t)(pk >> 32);
    float v = (x & 0x80000000u) ? __uint_as_float(x & 0x7fffffffu)
                                : __uint_as_float(~x);
    int j = (int)(~(uint32_t)pk);
    float sb = sumsq_b[j];
    float denb = sqrtf(sb + EPSF) + EPSF;
    float dot = v * denb * (1.0f / 128.0f);
    float cs = dot / ((sqrtf(sumsq_a[i]) + EPSF) * (sqrtf(sb) + EPSF));
    float term = 1.0f - cs;
#pragma unroll
    for (int m = 32; m; m >>= 1) term += __shfl_down(term, m, 64);
    __shared__ float red[4];
    int wv = threadIdx.x >> 6, lane = threadIdx.x & 63;
    if (lane == 0) red[wv] = term;
    __syncthreads();
    if (threadIdx.x == 0) {
        float ssum = (red[0] + red[1] + red[2] + red[3]) * (1.0f / HW);
        atomicAdd(out, ssum);
    }
}

extern "C" void kernel_launch(void* const* d_in, const int* in_sizes, int n_in,
                              void* d_out, int out_size, void* d_ws, size_t ws_size,
                              hipStream_t stream) {
    const float* a = (const float*)d_in[0];
    const float* b = (const float*)d_in[1];
    char* ws = (char*)d_ws;

    const size_t T_BYTES = (size_t)HW * CDIM;   // 12.58 MB per fp8 matrix
    uint8_t* at8 = (uint8_t*)ws;
    uint8_t* bn8 = (uint8_t*)(ws + T_BYTES);
    float* sumsq_a = (float*)(ws + 2 * T_BYTES);
    float* sumsq_b = (float*)(ws + 2 * T_BYTES + HW * sizeof(float));
    unsigned long long* best =
        (unsigned long long*)(ws + 2 * T_BYTES + 2 * HW * sizeof(float));
    float* invdb = (float*)(ws + 2 * T_BYTES + 2 * HW * sizeof(float)
                            + HW * sizeof(unsigned long long));

    // zero only best (sumsq/invdb are plain-stored by transpose now)
    hipMemsetAsync(best, 0, HW * sizeof(unsigned long long), stream);
    hipMemsetAsync(d_out, 0, out_size * sizeof(float), stream);

    dim3 tg(HW / 64, 1, 2);
    transpose_fp8_norm<<<tg, 256, 0, stream>>>(a, b, at8, bn8,
                                               sumsq_a, sumsq_b, invdb);
    gemm_argmax<<<(HW / 128) * (HW / 128), 256, 0, stream>>>(at8, bn8, invdb, best);
    loss_reduce<<<HW / 256, 256, 0, stream>>>(best, sumsq_a, sumsq_b, (float*)d_out);
}

// Round 10
// 378.674 us; speedup vs baseline: 1.2073x; 1.0087x over previous
//
#include <hip/hip_runtime.h>
#include <stdint.h>

#define HW 16384
#define CDIM 768
#define EPSF 1e-8f

typedef float f32x4  __attribute__((ext_vector_type(4)));
typedef float f32x16 __attribute__((ext_vector_type(16)));
typedef int   i32x8  __attribute__((ext_vector_type(8)));
typedef uint32_t u32x4 __attribute__((ext_vector_type(4)));

__device__ inline void async16(const void* g, void* l) {
    __builtin_amdgcn_global_load_lds(
        (const __attribute__((address_space(1))) uint32_t*)g,
        (__attribute__((address_space(3))) uint32_t*)l, 16, 0, 0);
}

__device__ inline uint32_t pk4_fp8(float v0, float v1, float v2, float v3) {
    uint32_t r = __builtin_amdgcn_cvt_pk_fp8_f32(v0, v1, 0, false);
    r = __builtin_amdgcn_cvt_pk_fp8_f32(v2, v3, r, true);
    return r;   // bytes [v0,v1,v2,v3] little-endian
}

// ---- Kernel 1: fused transpose [C][HW] fp32 -> [HW][C] fp8 + PARTIAL sum-sq ----
// Round 18: transpose measured ~85us vs ~20us HBM floor (125 MB at 16% BW,
// latency-bound). Root cause history: r0-r8 used full 2D grid but global
// ATOMICS for the channel reduction; r9 kept plain stores but serialized
// (512 blocks, 2/CU, 24 barriers/block) -- both ~85us. Fix: decouple.
// Full 2D grid (256 s x 12 cb x 2 z = 6144 blocks -> 8 blocks/CU, 100%
// wave occupancy), float4 loads, and the per-(cb,s) sum-sq partial goes
// to a 1.5 MB scratch array with a PLAIN STORE. A tiny fold kernel sums
// the 12 partials per spatial point afterward. No atomics, no serial loop.
// z=0: a (scale x16), z=1: b (scale x8, RAW; normalization in epilogue).
__global__ void __launch_bounds__(256)
transpose_fp8_part(const float* __restrict__ a, const float* __restrict__ b,
                   uint8_t* __restrict__ at8, uint8_t* __restrict__ bn8,
                   float* __restrict__ part) {
    const int z = blockIdx.z;
    const float* src = z ? b : a;
    uint8_t* dst = z ? bn8 : at8;
    const float mult = z ? 8.0f : 16.0f;

    __shared__ float tile[64][65];   // [channel][spatial], +1 pad
    const int s0 = blockIdx.x * 64, c0 = blockIdx.y * 64;

    // load: 16 lanes x float4 = 64 spatial per channel row; 16 rows/pass
    const int lane16 = threadIdx.x & 15, crow = threadIdx.x >> 4;
#pragma unroll
    for (int p = 0; p < 4; ++p) {
        int cl = p * 16 + crow;
        f32x4 v = *(const f32x4*)&src[(size_t)(c0 + cl) * HW + s0 + lane16 * 4];
        tile[cl][lane16 * 4 + 0] = v[0];
        tile[cl][lane16 * 4 + 1] = v[1];
        tile[cl][lane16 * 4 + 2] = v[2];
        tile[cl][lane16 * 4 + 3] = v[3];
    }
    __syncthreads();

    const int tx = threadIdx.x & 63, ty = threadIdx.x >> 6;
    const int chgrp = tx & 15, rowsub = tx >> 4;
    uint32_t* dst32 = (uint32_t*)dst;
    float* prow = part + ((size_t)z * 12 + blockIdx.y) * HW + s0;
#pragma unroll
    for (int p = 0; p < 4; ++p) {
        int sl = p * 16 + ty * 4 + rowsub;
        float v0 = tile[chgrp * 4 + 0][sl];
        float v1 = tile[chgrp * 4 + 1][sl];
        float v2 = tile[chgrp * 4 + 2][sl];
        float v3 = tile[chgrp * 4 + 3][sl];
        float ps = v0 * v0 + v1 * v1 + v2 * v2 + v3 * v3;   // raw sum-sq
        dst32[(size_t)(s0 + sl) * (CDIM / 4) + (c0 >> 2) + chgrp] =
            pk4_fp8(v0 * mult, v1 * mult, v2 * mult, v3 * mult);
#pragma unroll
        for (int m = 1; m < 16; m <<= 1) ps += __shfl_xor(ps, m, 64);
        if (chgrp == 0) prow[sl] = ps;                      // plain store
    }
}

// ---- Kernel 1b: fold 12 partials per spatial -> sumsq + invdb ----
// part[z][cb][s], cb-stride HW: reads coalesced across threads. 1.5 MB.
__global__ void __launch_bounds__(256)
fold_sums(const float* __restrict__ part, float* __restrict__ sumsq_a,
          float* __restrict__ sumsq_b, float* __restrict__ invdb) {
    int idx = blockIdx.x * 256 + threadIdx.x;   // 0 .. 2*HW-1
    int z = idx >> 14, s = idx & (HW - 1);
    const float* p = part + (size_t)z * 12 * HW + s;
    float t = 0.0f;
#pragma unroll
    for (int cb = 0; cb < 12; ++cb) t += p[(size_t)cb * HW];
    if (z) {
        sumsq_b[s] = t;
        invdb[s] = 1.0f / (sqrtf(t + EPSF) + EPSF);
    } else {
        sumsq_a[s] = t;
    }
}

// ---- Kernel 2: MX-scaled fp8 GEMM + normalize + argmax epilogue ----
// UNCHANGED from round 9 (session-best GEMM, 282us, verified 10x).
// Drain-per-tile + ~44% occupancy = the established optimum; counted-vmcnt
// across barriers struck (0-for-3). Geometry: 128x128 block, 4 waves,
// 64x64 wave tile, 64 VGPR + 64 AGPR. BK=64 double-buffer: STAGE(t+1)
// before COMPUTE(t), vmcnt(0) after compute + raw s_barrier.
// Swizzle involution (64B rows): write chunk (lane&3)^((lane>>3)&3),
// read key ^((l31>>1)&3). Swapped operands -> lane-local argmax.
// C/D 32x32: col=lane&31, row=(reg&3)+8*(reg>>2)+4*(lane>>5).
// Sentinels: WRITE_SIZE 33MB, conflicts 2.517e7, FETCH 204MB.
__global__ void
gemm_argmax(const uint8_t* __restrict__ at8, const uint8_t* __restrict__ bn8,
            const float* __restrict__ invdb,
            unsigned long long* __restrict__ best) {
    __shared__ uint8_t Al[2 * 8192];   // [buf][128 rows][64 B]
    __shared__ uint8_t Bl[2 * 8192];

    const int g = blockIdx.x;          // 0..16383
    const int xcd    = g & 7;
    const int s      = g >> 3;
    const int super  = s >> 5;         // 32 blocks / supertile
    const int within = s & 31;
    const int si = super >> 4;         // 4 i-tiles per supertile row
    const int sj = super & 15;         // 8 j-tiles per supertile col
    const int it = xcd * 16 + si * 4 + (within & 3);
    const int jt = sj * 8 + (within >> 2);

    const int i0 = it * 128, j0 = jt * 128;
    const int tid = threadIdx.x;
    const int lane = tid & 63, w = tid >> 6;
    const int wi = w & 1, wj = w >> 1;
    const int l31 = lane & 31, hi = lane >> 5;

    f32x16 acc[2][2] = {};   // [nj][mi]: rows j (regs), cols i (lanes)

    const int srow = lane >> 2;
    const int schunk = ((lane & 3) ^ ((lane >> 3) & 3)) * 16;
    const uint8_t* gA = at8 + (size_t)(i0 + w * 32 + srow) * CDIM + schunk;
    const uint8_t* gB = bn8 + (size_t)(j0 + w * 32 + srow) * CDIM + schunk;
    uint8_t* lA = Al + w * 2048;       // this wave's 32 rows
    uint8_t* lB = Bl + w * 2048;

    const int rA0 = (wi * 64 + l31) * 64;
    const int rB0 = (wj * 64 + l31) * 64;
    const int c0 = ((hi * 2) ^ ((l31 >> 1) & 3)) * 16;   // second b128 at ^16

#define STAGE(bo, kk)                                         \
    do {                                                      \
        async16(gA + (kk),             lA + (bo));            \
        async16(gA + (kk) + 16 * CDIM, lA + (bo) + 1024);     \
        async16(gB + (kk),             lB + (bo));            \
        async16(gB + (kk) + 16 * CDIM, lB + (bo) + 1024);     \
    } while (0)

#define COMPUTE(bo)                                                          \
    do {                                                                     \
        i32x8 af0, af1, bg;                                                  \
        *(u32x4*)&af0       = *(const u32x4*)&Al[(bo) + rA0 + c0];           \
        *((u32x4*)&af0 + 1) = *(const u32x4*)&Al[(bo) + rA0 + (c0 ^ 16)];    \
        *(u32x4*)&af1       = *(const u32x4*)&Al[(bo) + rA0 + 2048 + c0];    \
        *((u32x4*)&af1 + 1) = *(const u32x4*)&Al[(bo) + rA0 + 2048 + (c0 ^ 16)]; \
        *(u32x4*)&bg        = *(const u32x4*)&Bl[(bo) + rB0 + c0];           \
        *((u32x4*)&bg + 1)  = *(const u32x4*)&Bl[(bo) + rB0 + (c0 ^ 16)];    \
        acc[0][0] = __builtin_amdgcn_mfma_scale_f32_32x32x64_f8f6f4(         \
            bg, af0, acc[0][0], 0, 0, 0, 0x7F7F7F7F, 0, 0x7F7F7F7F);         \
        acc[0][1] = __builtin_amdgcn_mfma_scale_f32_32x32x64_f8f6f4(         \
            bg, af1, acc[0][1], 0, 0, 0, 0x7F7F7F7F, 0, 0x7F7F7F7F);         \
        *(u32x4*)&bg        = *(const u32x4*)&Bl[(bo) + rB0 + 2048 + c0];    \
        *((u32x4*)&bg + 1)  = *(const u32x4*)&Bl[(bo) + rB0 + 2048 + (c0 ^ 16)]; \
        acc[1][0] = __builtin_amdgcn_mfma_scale_f32_32x32x64_f8f6f4(         \
            bg, af0, acc[1][0], 0, 0, 0, 0x7F7F7F7F, 0, 0x7F7F7F7F);         \
        acc[1][1] = __builtin_amdgcn_mfma_scale_f32_32x32x64_f8f6f4(         \
            bg, af1, acc[1][1], 0, 0, 0, 0x7F7F7F7F, 0, 0x7F7F7F7F);         \
    } while (0)

    // prologue: stage tile 0, drain, barrier
    STAGE(0, 0);
    asm volatile("s_waitcnt vmcnt(0)" ::: "memory");
    __builtin_amdgcn_s_barrier();

#pragma unroll 1
    for (int t = 0; t < 11; ++t) {
        const int bo = (t & 1) * 8192;
        STAGE(bo ^ 8192, (t + 1) * 64);   // issue next tile (latency hides
        COMPUTE(bo);                      //   under this compute phase)
        asm volatile("s_waitcnt vmcnt(0)" ::: "memory");  // next tile landed
        __builtin_amdgcn_s_barrier();
    }
    COMPUTE(8192);                        // t=11, no further staging

#undef STAGE
#undef COMPUTE

    // epilogue: normalize by per-j inv-denom (precomputed, reg-indexed),
    // lane-local argmax over the 32 j's, one hi-exchange + atomicMax.
    float bv[2] = {-1e30f, -1e30f};
    int   bj[2] = {0, 0};
#pragma unroll
    for (int nj = 0; nj < 2; ++nj) {
        const int jb = j0 + wj * 64 + nj * 32 + 4 * hi;
        f32x4 iv[4];
#pragma unroll
        for (int q = 0; q < 4; ++q)
            iv[q] = *(const f32x4*)&invdb[jb + 8 * q];
#pragma unroll
        for (int mi = 0; mi < 2; ++mi) {
#pragma unroll
            for (int r = 0; r < 16; ++r) {
                int j = jb + (r & 3) + 8 * (r >> 2);
                float v = acc[nj][mi][r] * iv[r >> 2][r & 3];
                if (v > bv[mi] || (v == bv[mi] && j < bj[mi])) {
                    bv[mi] = v; bj[mi] = j;
                }
            }
        }
    }
#pragma unroll
    for (int mi = 0; mi < 2; ++mi) {
        float ov = __shfl_xor(bv[mi], 32, 64);
        int   oj = __shfl_xor(bj[mi], 32, 64);
        if (ov > bv[mi] || (ov == bv[mi] && oj < bj[mi])) {
            bv[mi] = ov; bj[mi] = oj;
        }
        if (hi == 0) {
            int gi = i0 + wi * 64 + mi * 32 + l31;
            uint32_t u = __float_as_uint(bv[mi]);
            u = (u & 0x80000000u) ? ~u : (u | 0x80000000u);  // orderable f32
            unsigned long long packed =
                ((unsigned long long)u << 32) | (uint32_t)(~(uint32_t)bj[mi]);
            atomicMax(&best[gi], packed);  // ties -> larger ~j -> smaller j
        }
    }
}

// ---- Kernel 3: final loss from stored argmax dot (no gather) ----
// stored v = 128 * dot(a_i, b_j) / denom_b[j]  (fp8 dot, fp32 denom)
__global__ void loss_reduce(const unsigned long long* __restrict__ best,
                            const float* __restrict__ sumsq_a,
                            const float* __restrict__ sumsq_b,
                            float* __restrict__ out) {
    int i = blockIdx.x * 256 + threadIdx.x;
    unsigned long long pk = best[i];
    uint32_t x = (uint32_t)(pk >> 32);
    float v = (x & 0x80000000u) ? __uint_as_float(x & 0x7fffffffu)
                                : __uint_as_float(~x);
    int j = (int)(~(uint32_t)pk);
    float sb = sumsq_b[j];
    float denb = sqrtf(sb + EPSF) + EPSF;
    float dot = v * denb * (1.0f / 128.0f);
    float cs = dot / ((sqrtf(sumsq_a[i]) + EPSF) * (sqrtf(sb) + EPSF));
    float term = 1.0f - cs;
#pragma unroll
    for (int m = 32; m; m >>= 1) term += __shfl_down(term, m, 64);
    __shared__ float red[4];
    int wv = threadIdx.x >> 6, lane = threadIdx.x & 63;
    if (lane == 0) red[wv] = term;
    __syncthreads();
    if (threadIdx.x == 0) {
        float ssum = (red[0] + red[1] + red[2] + red[3]) * (1.0f / HW);
        atomicAdd(out, ssum);
    }
}

extern "C" void kernel_launch(void* const* d_in, const int* in_sizes, int n_in,
                              void* d_out, int out_size, void* d_ws, size_t ws_size,
                              hipStream_t stream) {
    const float* a = (const float*)d_in[0];
    const float* b = (const float*)d_in[1];
    char* ws = (char*)d_ws;

    const size_t T_BYTES = (size_t)HW * CDIM;   // 12.58 MB per fp8 matrix
    uint8_t* at8 = (uint8_t*)ws;
    uint8_t* bn8 = (uint8_t*)(ws + T_BYTES);
    float* sumsq_a = (float*)(ws + 2 * T_BYTES);
    float* sumsq_b = (float*)(ws + 2 * T_BYTES + HW * sizeof(float));
    unsigned long long* best =
        (unsigned long long*)(ws + 2 * T_BYTES + 2 * HW * sizeof(float));
    float* invdb = (float*)(ws + 2 * T_BYTES + 2 * HW * sizeof(float)
                            + HW * sizeof(unsigned long long));
    float* part = (float*)(ws + 2 * T_BYTES + 2 * HW * sizeof(float)
                           + HW * sizeof(unsigned long long) + HW * sizeof(float));

    // zero only best (+ output); sums are plain-stored now
    hipMemsetAsync(best, 0, HW * sizeof(unsigned long long), stream);
    hipMemsetAsync(d_out, 0, out_size * sizeof(float), stream);

    dim3 tg(HW / 64, CDIM / 64, 2);
    transpose_fp8_part<<<tg, 256, 0, stream>>>(a, b, at8, bn8, part);
    fold_sums<<<2 * HW / 256, 256, 0, stream>>>(part, sumsq_a, sumsq_b, invdb);
    gemm_argmax<<<(HW / 128) * (HW / 128), 256, 0, stream>>>(at8, bn8, invdb, best);
    loss_reduce<<<HW / 256, 256, 0, stream>>>(best, sumsq_a, sumsq_b, (float*)d_out);
}